// Round 10
// baseline (812.561 us; speedup 1.0000x reference)
//
#include <hip/hip_runtime.h>
#include <hip/hip_bf16.h>
#include <cstdint>
#include <cstddef>

// Problem dims
#define HD   768
#define ID   3072
#define NB   4
#define SL   2048
#define NL   4
#define ROWS (NB*SL)   // 8192

typedef __attribute__((ext_vector_type(8))) short bf16x8s;
typedef __attribute__((ext_vector_type(4))) float f32x4;
typedef __attribute__((ext_vector_type(4))) unsigned short u16x4;

typedef __attribute__((address_space(1))) const unsigned int g_as1_u32;
typedef __attribute__((address_space(3))) unsigned int lds_as3_u32;

// async 16B/lane global->LDS copy (wave-uniform LDS base + lane*16)
__device__ __forceinline__ void gl2lds16(__hip_bfloat16* l, const __hip_bfloat16* g) {
  __builtin_amdgcn_global_load_lds((g_as1_u32*)g, (lds_as3_u32*)l, 16, 0, 0);
}

__device__ __forceinline__ float bfu2f(unsigned short u) {
  return __uint_as_float((unsigned int)u << 16);
}
__device__ __forceinline__ unsigned short f2bfu(float f) {
  __hip_bfloat16 h = __float2bfloat16(f);
  return *reinterpret_cast<unsigned short*>(&h);
}

// ---------------------------------------------------------------------------
// Wave-per-row LayerNorm: block=256 (4 waves), wave w does row blockIdx*4+w.
// ---------------------------------------------------------------------------
template <int OUTF32>
__global__ __launch_bounds__(256) void ln_row_kernel(
    const __hip_bfloat16* __restrict__ x,
    const float* __restrict__ scale, const float* __restrict__ bias,
    __hip_bfloat16* __restrict__ ob, float* __restrict__ of)
{
  const int w = threadIdx.x >> 6, lane = threadIdx.x & 63;
  const size_t row = (size_t)blockIdx.x * 4 + w;
  const __hip_bfloat16* xr = x + row * HD;
  float v[12];
#pragma unroll
  for (int c = 0; c < 3; c++) {
    u16x4 u = *reinterpret_cast<const u16x4*>(xr + c * 256 + lane * 4);
#pragma unroll
    for (int i = 0; i < 4; i++) v[c * 4 + i] = bfu2f(u[i]);
  }
  float s = 0.f;
#pragma unroll
  for (int i = 0; i < 12; i++) s += v[i];
#pragma unroll
  for (int m = 1; m < 64; m <<= 1) s += __shfl_xor(s, m);
  float mean = s * (1.0f / 768.0f);
  float q = 0.f;
#pragma unroll
  for (int i = 0; i < 12; i++) { float d = v[i] - mean; q += d * d; }
#pragma unroll
  for (int m = 1; m < 64; m <<= 1) q += __shfl_xor(q, m);
  float rstd = rsqrtf(q * (1.0f / 768.0f) + 1e-5f);
#pragma unroll
  for (int c = 0; c < 3; c++) {
    int j0 = c * 256 + lane * 4;
    if (OUTF32) {
      f32x4 o;
#pragma unroll
      for (int i = 0; i < 4; i++)
        o[i] = (v[c * 4 + i] - mean) * rstd * scale[j0 + i] + bias[j0 + i];
      *reinterpret_cast<f32x4*>(of + row * HD + j0) = o;
    } else {
      u16x4 o;
#pragma unroll
      for (int i = 0; i < 4; i++)
        o[i] = f2bfu((v[c * 4 + i] - mean) * rstd * scale[j0 + i] + bias[j0 + i]);
      *reinterpret_cast<u16x4*>(ob + row * HD + j0) = o;
    }
  }
}

// embedding gather + pos add + LN (wave-per-row), writes bf16
__global__ __launch_bounds__(256) void embed_ln_kernel(
    const int* __restrict__ ids, const float* __restrict__ wemb,
    const float* __restrict__ pemb,
    const float* __restrict__ scale, const float* __restrict__ bias,
    __hip_bfloat16* __restrict__ ob)
{
  const int w = threadIdx.x >> 6, lane = threadIdx.x & 63;
  const size_t row = (size_t)blockIdx.x * 4 + w;
  const int t = (int)(row & (SL - 1));
  const int id = ids[row];
  float v[12];
#pragma unroll
  for (int c = 0; c < 3; c++) {
    int j0 = c * 256 + lane * 4;
    f32x4 a = *reinterpret_cast<const f32x4*>(wemb + (size_t)id * HD + j0);
    f32x4 p = *reinterpret_cast<const f32x4*>(pemb + (size_t)t * HD + j0);
#pragma unroll
    for (int i = 0; i < 4; i++) v[c * 4 + i] = a[i] + p[i];
  }
  float s = 0.f;
#pragma unroll
  for (int i = 0; i < 12; i++) s += v[i];
#pragma unroll
  for (int m = 1; m < 64; m <<= 1) s += __shfl_xor(s, m);
  float mean = s * (1.0f / 768.0f);
  float q = 0.f;
#pragma unroll
  for (int i = 0; i < 12; i++) { float d = v[i] - mean; q += d * d; }
#pragma unroll
  for (int m = 1; m < 64; m <<= 1) q += __shfl_xor(q, m);
  float rstd = rsqrtf(q * (1.0f / 768.0f) + 1e-5f);
#pragma unroll
  for (int c = 0; c < 3; c++) {
    int j0 = c * 256 + lane * 4;
    u16x4 o;
#pragma unroll
    for (int i = 0; i < 4; i++)
      o[i] = f2bfu((v[c * 4 + i] - mean) * rstd * scale[j0 + i] + bias[j0 + i]);
    *reinterpret_cast<u16x4*>(ob + row * HD + j0) = o;
  }
}

// ---------------------------------------------------------------------------
// Weight transpose + f32->bf16: in [K][N] f32 -> out [N][K] bf16, grid.z = layer
// ---------------------------------------------------------------------------
__global__ __launch_bounds__(256) void transpose_bf16_kernel(
    const float* __restrict__ in, __hip_bfloat16* __restrict__ out, int K, int N)
{
  __shared__ float tile[32][33];
  const float* inp = in + (size_t)blockIdx.z * K * N;
  __hip_bfloat16* outp = out + (size_t)blockIdx.z * K * N;
  int n0 = blockIdx.x * 32, k0 = blockIdx.y * 32;
  int tx = threadIdx.x, ty = threadIdx.y;   // (32, 8)
#pragma unroll
  for (int i = 0; i < 4; i++)
    tile[ty + i * 8][tx] = inp[(size_t)(k0 + ty + i * 8) * N + n0 + tx];
  __syncthreads();
#pragma unroll
  for (int i = 0; i < 4; i++)
    outp[(size_t)(n0 + ty + i * 8) * K + k0 + tx] = __float2bfloat16(tile[tx][ty + i * 8]);
}

// ---------------------------------------------------------------------------
// Retention scan + residual fuse: r_t = 0.5*s_t + 0.5*r_{t-1};
// writes z = h + r (bf16). 64-chunk with 64-step warm-up (0.5^64 -> exact).
// ---------------------------------------------------------------------------
__global__ __launch_bounds__(256) void scan_kernel(
    const __hip_bfloat16* __restrict__ s,
    const __hip_bfloat16* __restrict__ h,
    __hip_bfloat16* __restrict__ z)
{
  int bid = blockIdx.x;             // b*96 + chunk*3 + sub
  int sub = bid % 3;
  int chunk = (bid / 3) % 32;
  int b = bid / 96;
  int hh = sub * 256 + threadIdx.x;
  int tstart = chunk * 64;
  int t0 = tstart - 64; if (t0 < 0) t0 = 0;
  const __hip_bfloat16* sp = s + (size_t)b * SL * HD + hh;
  const __hip_bfloat16* hp = h + (size_t)b * SL * HD + hh;
  __hip_bfloat16* zp = z + (size_t)b * SL * HD + hh;
  float acc = 0.f;
#pragma unroll 8
  for (int t = t0; t < tstart; ++t)
    acc = 0.5f * (__bfloat162float(sp[(size_t)t * HD]) + acc);
#pragma unroll 8
  for (int t = tstart; t < tstart + 64; ++t) {
    acc = 0.5f * (__bfloat162float(sp[(size_t)t * HD]) + acc);
    zp[(size_t)t * HD] = __float2bfloat16(acc + __bfloat162float(hp[(size_t)t * HD]));
  }
}

// ---------------------------------------------------------------------------
// 2-phase double-buffered MFMA GEMM, BM=256 / 8 waves (512 thr), BK=64.
// Wave grid 4M x 2N: wave w owns rows (w>>1)*64.., cols (w&1)*(BN/2)..
// LDS layout (round-7 proven): [kk][rows][32] per buffer, 64B row pitch.
//   A buffer: 2*256*32 elems (32KB); B buffer: 2*BN*32 (16/12KB).
//   dbuf total: 96KB (BN=128) / 88KB (BN=96) -> 1 block/CU, 2 waves/SIMD.
// Rationale: staged bytes = A*(N/BN) + B*(M/BM); BM 128->256 + larger BN
// cuts per-layer staging ~40% (GEMMs are ~L2/L3-staging-BW-bound).
// C[M,N] = act(A[M,K] @ Bt[N,K]^T + bias) [+ R], bf16 out.
// ---------------------------------------------------------------------------
template <int BN, int ACT, int RADD>
__global__ __launch_bounds__(512) void gemm_mfma_kernel(
    const __hip_bfloat16* __restrict__ A,
    const __hip_bfloat16* __restrict__ Bt,
    const float* __restrict__ bias,
    const __hip_bfloat16* __restrict__ R,
    __hip_bfloat16* __restrict__ Cb,
    int M, int N, int K)
{
  constexpr int NF = BN / 32;               // N-frags per wave: 4 or 3
  constexpr int AKK = 256 * 32;             // A kk-subtile elems (8192)
  constexpr int BKK = BN * 32;              // B kk-subtile elems
  constexpr int ABUF = 2 * AKK;             // per-buffer A elems (32KB)
  constexpr int BBUF = 2 * BKK;             // per-buffer B elems
  __shared__ __align__(16) __hip_bfloat16 As[2 * ABUF];
  __shared__ __align__(16) __hip_bfloat16 Bs[2 * BBUF];
  const int m0 = blockIdx.x * 256;
  const int n0 = blockIdx.y * BN;
  const int tid  = threadIdx.x;
  const int lane = tid & 63;
  const int w    = tid >> 6;                // wave 0..7
  const int wr   = w >> 1;                  // 0..3 (M quarter, 64 rows)
  const int wc   = w & 1;                   // 0..1 (N half)
  const int lr   = lane & 15;
  const int kg   = lane >> 4;               // 0..3

  f32x4 acc[4][NF];
#pragma unroll
  for (int i = 0; i < 4; i++)
#pragma unroll
    for (int j = 0; j < NF; j++) acc[i][j] = (f32x4){0.f, 0.f, 0.f, 0.f};

  // staging: one pass = 512 thr x 16B = 128 rows x 64B; wave w rows w*16..+15
  const int srow = (w << 4) + (lane >> 2);  // 0..127
  const int scol = (lane & 3) << 3;         // 0,8,16,24
  const __hip_bfloat16* aS = A  + (size_t)(m0 + srow) * K + scol;
  const __hip_bfloat16* bS = Bt + (size_t)(n0 + srow) * K + scol;
  const size_t K128 = (size_t)128 * K;
  const int ldsw = w << 9;                  // w*512 elems (16 rows x 32)

  auto stage = [&](int buf, int k0) {
    __hip_bfloat16* Ab = As + buf * ABUF + ldsw;
    __hip_bfloat16* Bb = Bs + buf * BBUF + ldsw;
#pragma unroll
    for (int kk = 0; kk < 2; kk++) {
      gl2lds16(Ab + kk * AKK,        aS + k0 + kk * 32);          // rows 0-127
      gl2lds16(Ab + kk * AKK + 4096, aS + k0 + kk * 32 + K128);   // rows 128-255
      if constexpr (BN == 128) {
        gl2lds16(Bb + kk * BKK, bS + k0 + kk * 32);               // rows 0-127
      } else if constexpr (BN == 96) {
        if (w < 6) gl2lds16(Bb + kk * BKK, bS + k0 + kk * 32);    // rows 0-95
      }
    }
  };

  const int arow = wr * 64 + lr;            // + i*16
  const int brow = wc * (BN / 2) + lr;      // + j*16

  auto compute = [&](int buf) {
    const __hip_bfloat16* Ab = As + buf * ABUF;
    const __hip_bfloat16* Bb = Bs + buf * BBUF;
#pragma unroll
    for (int kk = 0; kk < 2; kk++) {
      bf16x8s af[4], bq[NF];
#pragma unroll
      for (int i = 0; i < 4; i++)
        af[i] = *reinterpret_cast<const bf16x8s*>(
            &Ab[kk * AKK + (arow + i * 16) * 32 + kg * 8]);
#pragma unroll
      for (int j = 0; j < NF; j++)
        bq[j] = *reinterpret_cast<const bf16x8s*>(
            &Bb[kk * BKK + (brow + j * 16) * 32 + kg * 8]);
#pragma unroll
      for (int i = 0; i < 4; i++)
#pragma unroll
        for (int j = 0; j < NF; j++)
          acc[i][j] = __builtin_amdgcn_mfma_f32_16x16x32_bf16(af[i], bq[j], acc[i][j], 0, 0, 0);
    }
  };

  const int nt = K >> 6;                    // BK=64 tiles (12 or 48)
  stage(0, 0);
  __syncthreads();                          // prologue drain

  for (int t = 0; t < nt; ++t) {
    const int cur = t & 1;
    if (t + 1 < nt) stage(cur ^ 1, (t + 1) << 6);  // prefetch next tile
    compute(cur);
    __syncthreads();                        // drain: stage(t+1) + reads(t)
  }

#pragma unroll
  for (int i = 0; i < 4; i++)
#pragma unroll
    for (int j = 0; j < NF; j++) {
      int col = n0 + wc * (BN / 2) + j * 16 + lr;
      float bv = bias[col];
#pragma unroll
      for (int r = 0; r < 4; r++) {
        int row = m0 + wr * 64 + i * 16 + kg * 4 + r;
        float v = acc[i][j][r] + bv;
        if (ACT == 1) v = 1.f / (1.f + __expf(-v));
        else if (ACT == 2) {
          float x = v;
          float z = 1.5957691216057308f * (x + 0.044715f * x * x * x);
          v = x / (1.f + __expf(-z));
        }
        if (RADD) v += __bfloat162float(R[(size_t)row * N + col]);
        Cb[(size_t)row * N + col] = __float2bfloat16(v);
      }
    }
}

// ---------------------------------------------------------------------------
extern "C" void kernel_launch(void* const* d_in, const int* in_sizes, int n_in,
                              void* d_out, int out_size, void* d_ws, size_t ws_size,
                              hipStream_t stream)
{
  const int*   ids  = (const int*)d_in[0];
  const float* wemb = (const float*)d_in[1];
  const float* pemb = (const float*)d_in[2];
  const float* elns = (const float*)d_in[3];
  const float* elnb = (const float*)d_in[4];
  const float* retW = (const float*)d_in[5];
  const float* retb = (const float*)d_in[6];
  const float* ln1s = (const float*)d_in[7];
  const float* ln1b = (const float*)d_in[8];
  const float* W1   = (const float*)d_in[9];
  const float* b1   = (const float*)d_in[10];
  const float* W2   = (const float*)d_in[11];
  const float* b2   = (const float*)d_in[12];
  const float* ln2s = (const float*)d_in[13];
  const float* ln2b = (const float*)d_in[14];
  const float* fins = (const float*)d_in[15];
  const float* finb = (const float*)d_in[16];
  float* out = (float*)d_out;

  char* ws = (char*)d_ws;
  size_t off = 0;
  __hip_bfloat16* retWt = (__hip_bfloat16*)(ws + off); off += (size_t)NL * HD * HD * 2;
  __hip_bfloat16* W1t   = (__hip_bfloat16*)(ws + off); off += (size_t)NL * HD * ID * 2;
  __hip_bfloat16* W2t   = (__hip_bfloat16*)(ws + off); off += (size_t)NL * ID * HD * 2;
  __hip_bfloat16* hb    = (__hip_bfloat16*)(ws + off); off += (size_t)ROWS * HD * 2;  // residual h
  __hip_bfloat16* h1b   = (__hip_bfloat16*)(ws + off); off += (size_t)ROWS * HD * 2;  // h1
  __hip_bfloat16* zb    = (__hip_bfloat16*)(ws + off); off += (size_t)ROWS * HD * 2;  // h+r / h1+ffn2
  __hip_bfloat16* gb    = (__hip_bfloat16*)(ws + off); off += (size_t)ROWS * ID * 2;  // s / gelu out
  __hip_bfloat16* sb = gb;
  __hip_bfloat16* yb = zb;

  dim3 tb(32, 8);
  transpose_bf16_kernel<<<dim3(HD/32, HD/32, NL), tb, 0, stream>>>(retW, retWt, HD, HD);
  transpose_bf16_kernel<<<dim3(ID/32, HD/32, NL), tb, 0, stream>>>(W1, W1t, HD, ID);
  transpose_bf16_kernel<<<dim3(HD/32, ID/32, NL), tb, 0, stream>>>(W2, W2t, ID, HD);

  embed_ln_kernel<<<ROWS/4, 256, 0, stream>>>(ids, wemb, pemb, elns, elnb, hb);

  for (int l = 0; l < NL; l++) {
    // s = sigmoid(h @ retW + rb) -> sb (bf16). BM=256,BN=96 (256 blocks)
    gemm_mfma_kernel<96, 1, 0><<<dim3(ROWS/256, HD/96), 512, 0, stream>>>(
        hb, retWt + (size_t)l * HD * HD, retb + (size_t)l * HD,
        nullptr, sb, ROWS, HD, HD);
    // z = h + retention(s) -> zb (bf16)
    scan_kernel<<<NB * 32 * 3, 256, 0, stream>>>(sb, hb, zb);
    // h1 = LN(z)
    ln_row_kernel<0><<<ROWS/4, 256, 0, stream>>>(zb,
        ln1s + (size_t)l * HD, ln1b + (size_t)l * HD, h1b, nullptr);
    // g = gelu(h1 @ W1 + b1) -> gb (bf16). BM=256,BN=128 (768 blocks)
    gemm_mfma_kernel<128, 2, 0><<<dim3(ROWS/256, ID/128), 512, 0, stream>>>(
        h1b, W1t + (size_t)l * ID * HD, b1 + (size_t)l * ID,
        nullptr, gb, ROWS, ID, HD);
    // y = h1 + (g @ W2 + b2) -> yb (bf16). BM=256,BN=96 (256 blocks)
    gemm_mfma_kernel<96, 0, 1><<<dim3(ROWS/256, HD/96), 512, 0, stream>>>(
        gb, W2t + (size_t)l * HD * ID, b2 + (size_t)l * HD,
        h1b, yb, ROWS, HD, ID);
    // h = LN(y)
    ln_row_kernel<0><<<ROWS/4, 256, 0, stream>>>(yb,
        ln2s + (size_t)l * HD, ln2b + (size_t)l * HD, hb, nullptr);
  }
  // final LN -> d_out (f32)
  ln_row_kernel<1><<<ROWS/4, 256, 0, stream>>>(hb, fins, finb, nullptr, out);
}

// Round 11
// 638.426 us; speedup vs baseline: 1.2728x; 1.2728x over previous
//
#include <hip/hip_runtime.h>
#include <hip/hip_bf16.h>
#include <cstdint>
#include <cstddef>

// Problem dims
#define HD   768
#define ID   3072
#define NB   4
#define SL   2048
#define NL   4
#define ROWS (NB*SL)   // 8192

typedef __attribute__((ext_vector_type(8))) short bf16x8s;
typedef __attribute__((ext_vector_type(4))) float f32x4;
typedef __attribute__((ext_vector_type(4))) unsigned short u16x4;

typedef __attribute__((address_space(1))) const unsigned int g_as1_u32;
typedef __attribute__((address_space(3))) unsigned int lds_as3_u32;

// async 16B/lane global->LDS copy (wave-uniform LDS base + lane*16)
__device__ __forceinline__ void gl2lds16(__hip_bfloat16* l, const __hip_bfloat16* g) {
  __builtin_amdgcn_global_load_lds((g_as1_u32*)g, (lds_as3_u32*)l, 16, 0, 0);
}

__device__ __forceinline__ float bfu2f(unsigned short u) {
  return __uint_as_float((unsigned int)u << 16);
}
__device__ __forceinline__ unsigned short f2bfu(float f) {
  __hip_bfloat16 h = __float2bfloat16(f);
  return *reinterpret_cast<unsigned short*>(&h);
}

// ---------------------------------------------------------------------------
// Wave-per-row LayerNorm: block=256 (4 waves), wave w does row blockIdx*4+w.
// ---------------------------------------------------------------------------
template <int OUTF32>
__global__ __launch_bounds__(256) void ln_row_kernel(
    const __hip_bfloat16* __restrict__ x,
    const float* __restrict__ scale, const float* __restrict__ bias,
    __hip_bfloat16* __restrict__ ob, float* __restrict__ of)
{
  const int w = threadIdx.x >> 6, lane = threadIdx.x & 63;
  const size_t row = (size_t)blockIdx.x * 4 + w;
  const __hip_bfloat16* xr = x + row * HD;
  float v[12];
#pragma unroll
  for (int c = 0; c < 3; c++) {
    u16x4 u = *reinterpret_cast<const u16x4*>(xr + c * 256 + lane * 4);
#pragma unroll
    for (int i = 0; i < 4; i++) v[c * 4 + i] = bfu2f(u[i]);
  }
  float s = 0.f;
#pragma unroll
  for (int i = 0; i < 12; i++) s += v[i];
#pragma unroll
  for (int m = 1; m < 64; m <<= 1) s += __shfl_xor(s, m);
  float mean = s * (1.0f / 768.0f);
  float q = 0.f;
#pragma unroll
  for (int i = 0; i < 12; i++) { float d = v[i] - mean; q += d * d; }
#pragma unroll
  for (int m = 1; m < 64; m <<= 1) q += __shfl_xor(q, m);
  float rstd = rsqrtf(q * (1.0f / 768.0f) + 1e-5f);
#pragma unroll
  for (int c = 0; c < 3; c++) {
    int j0 = c * 256 + lane * 4;
    if (OUTF32) {
      f32x4 o;
#pragma unroll
      for (int i = 0; i < 4; i++)
        o[i] = (v[c * 4 + i] - mean) * rstd * scale[j0 + i] + bias[j0 + i];
      *reinterpret_cast<f32x4*>(of + row * HD + j0) = o;
    } else {
      u16x4 o;
#pragma unroll
      for (int i = 0; i < 4; i++)
        o[i] = f2bfu((v[c * 4 + i] - mean) * rstd * scale[j0 + i] + bias[j0 + i]);
      *reinterpret_cast<u16x4*>(ob + row * HD + j0) = o;
    }
  }
}

// embedding gather + pos add + LN (wave-per-row), writes bf16
__global__ __launch_bounds__(256) void embed_ln_kernel(
    const int* __restrict__ ids, const float* __restrict__ wemb,
    const float* __restrict__ pemb,
    const float* __restrict__ scale, const float* __restrict__ bias,
    __hip_bfloat16* __restrict__ ob)
{
  const int w = threadIdx.x >> 6, lane = threadIdx.x & 63;
  const size_t row = (size_t)blockIdx.x * 4 + w;
  const int t = (int)(row & (SL - 1));
  const int id = ids[row];
  float v[12];
#pragma unroll
  for (int c = 0; c < 3; c++) {
    int j0 = c * 256 + lane * 4;
    f32x4 a = *reinterpret_cast<const f32x4*>(wemb + (size_t)id * HD + j0);
    f32x4 p = *reinterpret_cast<const f32x4*>(pemb + (size_t)t * HD + j0);
#pragma unroll
    for (int i = 0; i < 4; i++) v[c * 4 + i] = a[i] + p[i];
  }
  float s = 0.f;
#pragma unroll
  for (int i = 0; i < 12; i++) s += v[i];
#pragma unroll
  for (int m = 1; m < 64; m <<= 1) s += __shfl_xor(s, m);
  float mean = s * (1.0f / 768.0f);
  float q = 0.f;
#pragma unroll
  for (int i = 0; i < 12; i++) { float d = v[i] - mean; q += d * d; }
#pragma unroll
  for (int m = 1; m < 64; m <<= 1) q += __shfl_xor(q, m);
  float rstd = rsqrtf(q * (1.0f / 768.0f) + 1e-5f);
#pragma unroll
  for (int c = 0; c < 3; c++) {
    int j0 = c * 256 + lane * 4;
    u16x4 o;
#pragma unroll
    for (int i = 0; i < 4; i++)
      o[i] = f2bfu((v[c * 4 + i] - mean) * rstd * scale[j0 + i] + bias[j0 + i]);
    *reinterpret_cast<u16x4*>(ob + row * HD + j0) = o;
  }
}

// ---------------------------------------------------------------------------
// Weight transpose + f32->bf16: in [K][N] f32 -> out [N][K] bf16, grid.z = layer
// ---------------------------------------------------------------------------
__global__ __launch_bounds__(256) void transpose_bf16_kernel(
    const float* __restrict__ in, __hip_bfloat16* __restrict__ out, int K, int N)
{
  __shared__ float tile[32][33];
  const float* inp = in + (size_t)blockIdx.z * K * N;
  __hip_bfloat16* outp = out + (size_t)blockIdx.z * K * N;
  int n0 = blockIdx.x * 32, k0 = blockIdx.y * 32;
  int tx = threadIdx.x, ty = threadIdx.y;   // (32, 8)
#pragma unroll
  for (int i = 0; i < 4; i++)
    tile[ty + i * 8][tx] = inp[(size_t)(k0 + ty + i * 8) * N + n0 + tx];
  __syncthreads();
#pragma unroll
  for (int i = 0; i < 4; i++)
    outp[(size_t)(n0 + ty + i * 8) * K + k0 + tx] = __float2bfloat16(tile[tx][ty + i * 8]);
}

// ---------------------------------------------------------------------------
// Retention scan + residual fuse: r_t = 0.5*s_t + 0.5*r_{t-1};
// writes z = h + r (bf16). 64-chunk with 64-step warm-up (0.5^64 -> exact).
// ---------------------------------------------------------------------------
__global__ __launch_bounds__(256) void scan_kernel(
    const __hip_bfloat16* __restrict__ s,
    const __hip_bfloat16* __restrict__ h,
    __hip_bfloat16* __restrict__ z)
{
  int bid = blockIdx.x;             // b*96 + chunk*3 + sub
  int sub = bid % 3;
  int chunk = (bid / 3) % 32;
  int b = bid / 96;
  int hh = sub * 256 + threadIdx.x;
  int tstart = chunk * 64;
  int t0 = tstart - 64; if (t0 < 0) t0 = 0;
  const __hip_bfloat16* sp = s + (size_t)b * SL * HD + hh;
  const __hip_bfloat16* hp = h + (size_t)b * SL * HD + hh;
  __hip_bfloat16* zp = z + (size_t)b * SL * HD + hh;
  float acc = 0.f;
#pragma unroll 8
  for (int t = t0; t < tstart; ++t)
    acc = 0.5f * (__bfloat162float(sp[(size_t)t * HD]) + acc);
#pragma unroll 8
  for (int t = tstart; t < tstart + 64; ++t) {
    acc = 0.5f * (__bfloat162float(sp[(size_t)t * HD]) + acc);
    zp[(size_t)t * HD] = __float2bfloat16(acc + __bfloat162float(hp[(size_t)t * HD]));
  }
}

// ---------------------------------------------------------------------------
// 8-phase-lite counted-vmcnt MFMA GEMM. BM=256, 8 waves (512 thr), BK=64.
// Per K-step: vmcnt(L) [tile t's loads done; t+1's stay in flight] ->
//   s_barrier -> ds_read ALL frags of t to regs -> lgkmcnt(0) -> s_barrier ->
//   stage(t+2) into the just-read buffer (2 buffers) -> MFMA cluster.
// No vmcnt(0) drain in steady state; loads span ~1.5 compute phases.
// T2 slot-XOR swizzle (r9-proven): LDS [rows][64] (128B pitch), linear dest,
// inverse-swizzled global src slot (l&7)^((l>>3)&7); read slot (kk*4+kg)^(lr&7).
// LDS dbuf: 96KB (BN=128) / 88KB (BN=96) -> 1 block/CU, 2 waves/SIMD.
// C[M,N] = act(A[M,K] @ Bt[N,K]^T + bias) [+ R], bf16 out.
// ---------------------------------------------------------------------------
template <int BN, int ACT, int RADD>
__global__ __launch_bounds__(512, 2) void gemm_mfma_kernel(
    const __hip_bfloat16* __restrict__ A,
    const __hip_bfloat16* __restrict__ Bt,
    const float* __restrict__ bias,
    const __hip_bfloat16* __restrict__ R,
    __hip_bfloat16* __restrict__ Cb,
    int M, int N, int K)
{
  constexpr int NF = BN / 32;               // N-frags per wave: 4 or 3
  constexpr int ABUF = 256 * 64;            // A buffer elems (32KB)
  constexpr int BBUF = BN * 64;             // B buffer elems (16/12KB)
  __shared__ __align__(16) __hip_bfloat16 As[2 * ABUF];
  __shared__ __align__(16) __hip_bfloat16 Bs[2 * BBUF];
  const int m0 = blockIdx.x * 256;
  const int n0 = blockIdx.y * BN;
  const int tid  = threadIdx.x;
  const int lane = tid & 63;
  const int w    = tid >> 6;                // wave 0..7
  const int wr   = w >> 1;                  // 0..3 (M quarter, 64 rows)
  const int wc   = w & 1;                   // 0..1 (N half)
  const int lr   = lane & 15;
  const int kg   = lane >> 4;               // 0..3

  f32x4 acc[4][NF];
#pragma unroll
  for (int i = 0; i < 4; i++)
#pragma unroll
    for (int j = 0; j < NF; j++) acc[i][j] = (f32x4){0.f, 0.f, 0.f, 0.f};

  // staging: pass = 512 thr x 16B = 64 rows x 128B. Wave w rows w*8..w*8+7.
  // lane l: row w*8 + l/8, LDS slot l%8, global k-slot (l%8)^((l/8)&7).
  const int prow = lane >> 3;
  const int pslot = lane & 7;
  const int gslot = pslot ^ (prow & 7);
  const __hip_bfloat16* aS = A  + (size_t)(m0 + w * 8 + prow) * K + gslot * 8;
  const __hip_bfloat16* bS = Bt + (size_t)(n0 + w * 8 + prow) * K + gslot * 8;
  const size_t K64g = (size_t)64 * K;       // 64-row pass stride (global)
  const int ldsw = w << 9;                  // w*512 elems (8 rows x 64)

  auto stage = [&](int buf, int k0) {
    __hip_bfloat16* Ab = As + buf * ABUF + ldsw;
    __hip_bfloat16* Bb = Bs + buf * BBUF + ldsw;
    gl2lds16(Ab,          aS + k0);              // A rows 0-63
    gl2lds16(Ab + 4096,   aS + k0 + K64g);       // A rows 64-127
    gl2lds16(Ab + 8192,   aS + k0 + 2 * K64g);   // A rows 128-191
    gl2lds16(Ab + 12288,  aS + k0 + 3 * K64g);   // A rows 192-255
    gl2lds16(Bb,          bS + k0);              // B rows 0-63
    if constexpr (BN == 128) {
      gl2lds16(Bb + 4096, bS + k0 + K64g);       // B rows 64-127
    } else if constexpr (BN == 96) {
      if (w < 4) gl2lds16(Bb + 4096, bS + k0 + K64g);  // B rows 64-95
    }
  };

  // read-side swizzled slots (per-lane constants)
  const int rx = lr & 7;
  const int arow = wr * 64 + lr;            // + i*16
  const int brow = wc * (BN / 2) + lr;      // + j*16

  const int nt = K >> 6;                    // BK=64 tiles
  stage(0, 0);
  stage(1, 64);

  for (int t = 0; t < nt; ++t) {
    const int cur = t & 1;
    // counted wait: only tile t's own loads must be done (t+1's in flight)
    if (t == nt - 1) {
      asm volatile("s_waitcnt vmcnt(0)" ::: "memory");
    } else if constexpr (BN == 128) {
      asm volatile("s_waitcnt vmcnt(6)" ::: "memory");
    } else {
      asm volatile("s_waitcnt vmcnt(5)" ::: "memory");
    }
    asm volatile("s_barrier" ::: "memory");          // all waves: tile t ready

    const __hip_bfloat16* Ab = As + cur * ABUF;
    const __hip_bfloat16* Bb = Bs + cur * BBUF;
    bf16x8s af[2][4], bq[2][NF];
#pragma unroll
    for (int kk = 0; kk < 2; kk++) {
      const int sl = ((kk * 4 + kg) ^ rx) * 8;
#pragma unroll
      for (int i = 0; i < 4; i++)
        af[kk][i] = *reinterpret_cast<const bf16x8s*>(&Ab[(arow + i * 16) * 64 + sl]);
#pragma unroll
      for (int j = 0; j < NF; j++)
        bq[kk][j] = *reinterpret_cast<const bf16x8s*>(&Bb[(brow + j * 16) * 64 + sl]);
    }
    asm volatile("s_waitcnt lgkmcnt(0)" ::: "memory");  // frags in regs
    asm volatile("s_barrier" ::: "memory");             // all waves done reading

    if (t + 2 < nt) stage(cur, (t + 2) << 6);  // overwrite just-read buffer

#pragma unroll
    for (int kk = 0; kk < 2; kk++)
#pragma unroll
      for (int i = 0; i < 4; i++)
#pragma unroll
        for (int j = 0; j < NF; j++)
          acc[i][j] = __builtin_amdgcn_mfma_f32_16x16x32_bf16(
              af[kk][i], bq[kk][j], acc[i][j], 0, 0, 0);
  }

#pragma unroll
  for (int i = 0; i < 4; i++)
#pragma unroll
    for (int j = 0; j < NF; j++) {
      int col = n0 + wc * (BN / 2) + j * 16 + lr;
      float bv = bias[col];
#pragma unroll
      for (int r = 0; r < 4; r++) {
        int row = m0 + wr * 64 + i * 16 + kg * 4 + r;
        float v = acc[i][j][r] + bv;
        if (ACT == 1) v = 1.f / (1.f + __expf(-v));
        else if (ACT == 2) {
          float x = v;
          float z = 1.5957691216057308f * (x + 0.044715f * x * x * x);
          v = x / (1.f + __expf(-z));
        }
        if (RADD) v += __bfloat162float(R[(size_t)row * N + col]);
        Cb[(size_t)row * N + col] = __float2bfloat16(v);
      }
    }
}

// ---------------------------------------------------------------------------
extern "C" void kernel_launch(void* const* d_in, const int* in_sizes, int n_in,
                              void* d_out, int out_size, void* d_ws, size_t ws_size,
                              hipStream_t stream)
{
  const int*   ids  = (const int*)d_in[0];
  const float* wemb = (const float*)d_in[1];
  const float* pemb = (const float*)d_in[2];
  const float* elns = (const float*)d_in[3];
  const float* elnb = (const float*)d_in[4];
  const float* retW = (const float*)d_in[5];
  const float* retb = (const float*)d_in[6];
  const float* ln1s = (const float*)d_in[7];
  const float* ln1b = (const float*)d_in[8];
  const float* W1   = (const float*)d_in[9];
  const float* b1   = (const float*)d_in[10];
  const float* W2   = (const float*)d_in[11];
  const float* b2   = (const float*)d_in[12];
  const float* ln2s = (const float*)d_in[13];
  const float* ln2b = (const float*)d_in[14];
  const float* fins = (const float*)d_in[15];
  const float* finb = (const float*)d_in[16];
  float* out = (float*)d_out;

  char* ws = (char*)d_ws;
  size_t off = 0;
  __hip_bfloat16* retWt = (__hip_bfloat16*)(ws + off); off += (size_t)NL * HD * HD * 2;
  __hip_bfloat16* W1t   = (__hip_bfloat16*)(ws + off); off += (size_t)NL * HD * ID * 2;
  __hip_bfloat16* W2t   = (__hip_bfloat16*)(ws + off); off += (size_t)NL * ID * HD * 2;
  __hip_bfloat16* hb    = (__hip_bfloat16*)(ws + off); off += (size_t)ROWS * HD * 2;  // residual h
  __hip_bfloat16* h1b   = (__hip_bfloat16*)(ws + off); off += (size_t)ROWS * HD * 2;  // h1
  __hip_bfloat16* zb    = (__hip_bfloat16*)(ws + off); off += (size_t)ROWS * HD * 2;  // h+r / h1+ffn2
  __hip_bfloat16* gb    = (__hip_bfloat16*)(ws + off); off += (size_t)ROWS * ID * 2;  // s / gelu out
  __hip_bfloat16* sb = gb;
  __hip_bfloat16* yb = zb;

  dim3 tb(32, 8);
  transpose_bf16_kernel<<<dim3(HD/32, HD/32, NL), tb, 0, stream>>>(retW, retWt, HD, HD);
  transpose_bf16_kernel<<<dim3(ID/32, HD/32, NL), tb, 0, stream>>>(W1, W1t, HD, ID);
  transpose_bf16_kernel<<<dim3(HD/32, ID/32, NL), tb, 0, stream>>>(W2, W2t, ID, HD);

  embed_ln_kernel<<<ROWS/4, 256, 0, stream>>>(ids, wemb, pemb, elns, elnb, hb);

  for (int l = 0; l < NL; l++) {
    // s = sigmoid(h @ retW + rb) -> sb (bf16). BM=256,BN=96 (256 blocks)
    gemm_mfma_kernel<96, 1, 0><<<dim3(ROWS/256, HD/96), 512, 0, stream>>>(
        hb, retWt + (size_t)l * HD * HD, retb + (size_t)l * HD,
        nullptr, sb, ROWS, HD, HD);
    // z = h + retention(s) -> zb (bf16)
    scan_kernel<<<NB * 32 * 3, 256, 0, stream>>>(sb, hb, zb);
    // h1 = LN(z)
    ln_row_kernel<0><<<ROWS/4, 256, 0, stream>>>(zb,
        ln1s + (size_t)l * HD, ln1b + (size_t)l * HD, h1b, nullptr);
    // g = gelu(h1 @ W1 + b1) -> gb (bf16). BM=256,BN=128 (768 blocks)
    gemm_mfma_kernel<128, 2, 0><<<dim3(ROWS/256, ID/128), 512, 0, stream>>>(
        h1b, W1t + (size_t)l * ID * HD, b1 + (size_t)l * ID,
        nullptr, gb, ROWS, ID, HD);
    // y = h1 + (g @ W2 + b2) -> yb (bf16). BM=256,BN=96 (256 blocks)
    gemm_mfma_kernel<96, 0, 1><<<dim3(ROWS/256, HD/96), 512, 0, stream>>>(
        gb, W2t + (size_t)l * HD * ID, b2 + (size_t)l * HD,
        h1b, yb, ROWS, HD, ID);
    // h = LN(y)
    ln_row_kernel<0><<<ROWS/4, 256, 0, stream>>>(yb,
        ln2s + (size_t)l * HD, ln2b + (size_t)l * HD, hb, nullptr);
  }
  // final LN -> d_out (f32)
  ln_row_kernel<1><<<ROWS/4, 256, 0, stream>>>(hb, fins, finb, nullptr, out);
}

// Round 12
// 588.800 us; speedup vs baseline: 1.3800x; 1.0843x over previous
//
#include <hip/hip_runtime.h>
#include <hip/hip_bf16.h>
#include <cstdint>
#include <cstddef>

// Problem dims
#define HD   768
#define ID   3072
#define NB   4
#define SL   2048
#define NL   4
#define ROWS (NB*SL)   // 8192

typedef __attribute__((ext_vector_type(8))) short bf16x8s;
typedef __attribute__((ext_vector_type(4))) float f32x4;
typedef __attribute__((ext_vector_type(4))) unsigned short u16x4;

typedef __attribute__((address_space(1))) const unsigned int g_as1_u32;
typedef __attribute__((address_space(3))) unsigned int lds_as3_u32;

// async 16B/lane global->LDS copy (wave-uniform LDS base + lane*16)
__device__ __forceinline__ void gl2lds16(__hip_bfloat16* l, const __hip_bfloat16* g) {
  __builtin_amdgcn_global_load_lds((g_as1_u32*)g, (lds_as3_u32*)l, 16, 0, 0);
}

__device__ __forceinline__ float bfu2f(unsigned short u) {
  return __uint_as_float((unsigned int)u << 16);
}
__device__ __forceinline__ unsigned short f2bfu(float f) {
  __hip_bfloat16 h = __float2bfloat16(f);
  return *reinterpret_cast<unsigned short*>(&h);
}

// ---------------------------------------------------------------------------
// Wave-per-row LayerNorm: block=256 (4 waves), wave w does row blockIdx*4+w.
// ---------------------------------------------------------------------------
template <int OUTF32>
__global__ __launch_bounds__(256) void ln_row_kernel(
    const __hip_bfloat16* __restrict__ x,
    const float* __restrict__ scale, const float* __restrict__ bias,
    __hip_bfloat16* __restrict__ ob, float* __restrict__ of)
{
  const int w = threadIdx.x >> 6, lane = threadIdx.x & 63;
  const size_t row = (size_t)blockIdx.x * 4 + w;
  const __hip_bfloat16* xr = x + row * HD;
  float v[12];
#pragma unroll
  for (int c = 0; c < 3; c++) {
    u16x4 u = *reinterpret_cast<const u16x4*>(xr + c * 256 + lane * 4);
#pragma unroll
    for (int i = 0; i < 4; i++) v[c * 4 + i] = bfu2f(u[i]);
  }
  float s = 0.f;
#pragma unroll
  for (int i = 0; i < 12; i++) s += v[i];
#pragma unroll
  for (int m = 1; m < 64; m <<= 1) s += __shfl_xor(s, m);
  float mean = s * (1.0f / 768.0f);
  float q = 0.f;
#pragma unroll
  for (int i = 0; i < 12; i++) { float d = v[i] - mean; q += d * d; }
#pragma unroll
  for (int m = 1; m < 64; m <<= 1) q += __shfl_xor(q, m);
  float rstd = rsqrtf(q * (1.0f / 768.0f) + 1e-5f);
#pragma unroll
  for (int c = 0; c < 3; c++) {
    int j0 = c * 256 + lane * 4;
    if (OUTF32) {
      f32x4 o;
#pragma unroll
      for (int i = 0; i < 4; i++)
        o[i] = (v[c * 4 + i] - mean) * rstd * scale[j0 + i] + bias[j0 + i];
      *reinterpret_cast<f32x4*>(of + row * HD + j0) = o;
    } else {
      u16x4 o;
#pragma unroll
      for (int i = 0; i < 4; i++)
        o[i] = f2bfu((v[c * 4 + i] - mean) * rstd * scale[j0 + i] + bias[j0 + i]);
      *reinterpret_cast<u16x4*>(ob + row * HD + j0) = o;
    }
  }
}

// embedding gather + pos add + LN (wave-per-row), writes bf16
__global__ __launch_bounds__(256) void embed_ln_kernel(
    const int* __restrict__ ids, const float* __restrict__ wemb,
    const float* __restrict__ pemb,
    const float* __restrict__ scale, const float* __restrict__ bias,
    __hip_bfloat16* __restrict__ ob)
{
  const int w = threadIdx.x >> 6, lane = threadIdx.x & 63;
  const size_t row = (size_t)blockIdx.x * 4 + w;
  const int t = (int)(row & (SL - 1));
  const int id = ids[row];
  float v[12];
#pragma unroll
  for (int c = 0; c < 3; c++) {
    int j0 = c * 256 + lane * 4;
    f32x4 a = *reinterpret_cast<const f32x4*>(wemb + (size_t)id * HD + j0);
    f32x4 p = *reinterpret_cast<const f32x4*>(pemb + (size_t)t * HD + j0);
#pragma unroll
    for (int i = 0; i < 4; i++) v[c * 4 + i] = a[i] + p[i];
  }
  float s = 0.f;
#pragma unroll
  for (int i = 0; i < 12; i++) s += v[i];
#pragma unroll
  for (int m = 1; m < 64; m <<= 1) s += __shfl_xor(s, m);
  float mean = s * (1.0f / 768.0f);
  float q = 0.f;
#pragma unroll
  for (int i = 0; i < 12; i++) { float d = v[i] - mean; q += d * d; }
#pragma unroll
  for (int m = 1; m < 64; m <<= 1) q += __shfl_xor(q, m);
  float rstd = rsqrtf(q * (1.0f / 768.0f) + 1e-5f);
#pragma unroll
  for (int c = 0; c < 3; c++) {
    int j0 = c * 256 + lane * 4;
    u16x4 o;
#pragma unroll
    for (int i = 0; i < 4; i++)
      o[i] = f2bfu((v[c * 4 + i] - mean) * rstd * scale[j0 + i] + bias[j0 + i]);
    *reinterpret_cast<u16x4*>(ob + row * HD + j0) = o;
  }
}

// ---------------------------------------------------------------------------
// Weight transpose + f32->bf16: in [K][N] f32 -> out [N][K] bf16, grid.z = layer
// ---------------------------------------------------------------------------
__global__ __launch_bounds__(256) void transpose_bf16_kernel(
    const float* __restrict__ in, __hip_bfloat16* __restrict__ out, int K, int N)
{
  __shared__ float tile[32][33];
  const float* inp = in + (size_t)blockIdx.z * K * N;
  __hip_bfloat16* outp = out + (size_t)blockIdx.z * K * N;
  int n0 = blockIdx.x * 32, k0 = blockIdx.y * 32;
  int tx = threadIdx.x, ty = threadIdx.y;   // (32, 8)
#pragma unroll
  for (int i = 0; i < 4; i++)
    tile[ty + i * 8][tx] = inp[(size_t)(k0 + ty + i * 8) * N + n0 + tx];
  __syncthreads();
#pragma unroll
  for (int i = 0; i < 4; i++)
    outp[(size_t)(n0 + ty + i * 8) * K + k0 + tx] = __float2bfloat16(tile[tx][ty + i * 8]);
}

// ---------------------------------------------------------------------------
// Retention scan + residual fuse: r_t = 0.5*s_t + 0.5*r_{t-1};
// writes z = h + r (bf16). 64-chunk with 64-step warm-up (0.5^64 -> exact).
// ---------------------------------------------------------------------------
__global__ __launch_bounds__(256) void scan_kernel(
    const __hip_bfloat16* __restrict__ s,
    const __hip_bfloat16* __restrict__ h,
    __hip_bfloat16* __restrict__ z)
{
  int bid = blockIdx.x;             // b*96 + chunk*3 + sub
  int sub = bid % 3;
  int chunk = (bid / 3) % 32;
  int b = bid / 96;
  int hh = sub * 256 + threadIdx.x;
  int tstart = chunk * 64;
  int t0 = tstart - 64; if (t0 < 0) t0 = 0;
  const __hip_bfloat16* sp = s + (size_t)b * SL * HD + hh;
  const __hip_bfloat16* hp = h + (size_t)b * SL * HD + hh;
  __hip_bfloat16* zp = z + (size_t)b * SL * HD + hh;
  float acc = 0.f;
#pragma unroll 8
  for (int t = t0; t < tstart; ++t)
    acc = 0.5f * (__bfloat162float(sp[(size_t)t * HD]) + acc);
#pragma unroll 8
  for (int t = tstart; t < tstart + 64; ++t) {
    acc = 0.5f * (__bfloat162float(sp[(size_t)t * HD]) + acc);
    zp[(size_t)t * HD] = __float2bfloat16(acc + __bfloat162float(hp[(size_t)t * HD]));
  }
}

// ---------------------------------------------------------------------------
// Counted-vmcnt pipelined MFMA GEMM at 2-blocks/CU geometry.
// BM=128, 4 waves (256 thr), BK=64, 2 LDS buffers.
// Per K-step: vmcnt(L) [only tile t's own 8|7 loads must be done; t+1's
//   stay in flight] -> s_barrier -> ds_read ALL frags of t to regs ->
//   lgkmcnt(0) -> s_barrier -> stage(t+2) into just-read buffer -> MFMAs.
// No vmcnt(0) drain in steady state; loads span ~1.5 compute phases, and
// 2 co-resident blocks/CU cover the remaining exposed latency.
// T2 slot-XOR swizzle: LDS [rows][64] (128B pitch), linear dest,
// inverse-swizzled global src slot (l&7)^(l>>3); read slot (kk*4+kg)^(lr&7)
// -> 2-way bank spread (free). Involution verified (r9/r11 refchecks).
// LDS dbuf: 64KB (BN=128) / 56KB (BN=96) -> 2 blocks/CU.
// C[M,N] = act(A[M,K] @ Bt[N,K]^T + bias) [+ R], bf16 out.
// ---------------------------------------------------------------------------
template <int BN, int ACT, int RADD>
__global__ __launch_bounds__(256, 2) void gemm_mfma_kernel(
    const __hip_bfloat16* __restrict__ A,
    const __hip_bfloat16* __restrict__ Bt,
    const float* __restrict__ bias,
    const __hip_bfloat16* __restrict__ R,
    __hip_bfloat16* __restrict__ Cb,
    int M, int N, int K)
{
  constexpr int NF = BN / 32;               // N-frags per wave: 4 or 3
  constexpr int ABUF = 128 * 64;            // A buffer elems (16KB)
  constexpr int BBUF = BN * 64;             // B buffer elems (16/12KB)
  __shared__ __align__(16) __hip_bfloat16 As[2 * ABUF];
  __shared__ __align__(16) __hip_bfloat16 Bs[2 * BBUF];
  const int m0 = blockIdx.x * 128;
  const int n0 = blockIdx.y * BN;
  const int tid  = threadIdx.x;
  const int lane = tid & 63;
  const int w    = tid >> 6;                // wave 0..3
  const int wr   = w >> 1;                  // 0..1 (M half, 64 rows)
  const int wc   = w & 1;                   // 0..1 (N half)
  const int lr   = lane & 15;
  const int kg   = lane >> 4;               // 0..3

  f32x4 acc[4][NF];
#pragma unroll
  for (int i = 0; i < 4; i++)
#pragma unroll
    for (int j = 0; j < NF; j++) acc[i][j] = (f32x4){0.f, 0.f, 0.f, 0.f};

  // staging: pass = 256 thr x 16B = 32 rows x 128B. Wave w rows w*8..w*8+7.
  // lane l: row w*8 + l/8, LDS slot l%8, global k-slot (l%8)^(l/8).
  const int prow = lane >> 3;               // 0..7
  const int pslot = lane & 7;
  const int gslot = pslot ^ prow;
  const __hip_bfloat16* aS = A  + (size_t)(m0 + w * 8 + prow) * K + gslot * 8;
  const __hip_bfloat16* bS = Bt + (size_t)(n0 + w * 8 + prow) * K + gslot * 8;
  const size_t K32g = (size_t)32 * K;       // 32-row pass stride (global)
  const int ldsw = w << 9;                  // w*512 elems (8 rows x 64)

  // per-wave loads per stage: A 4 passes + B NF passes = 8 (BN=128) / 7 (96)
  auto stage = [&](int buf, int k0) {
    __hip_bfloat16* Ab = As + buf * ABUF + ldsw;
    __hip_bfloat16* Bb = Bs + buf * BBUF + ldsw;
    gl2lds16(Ab,         aS + k0);               // A rows 0-31
    gl2lds16(Ab + 2048,  aS + k0 + K32g);        // A rows 32-63
    gl2lds16(Ab + 4096,  aS + k0 + 2 * K32g);    // A rows 64-95
    gl2lds16(Ab + 6144,  aS + k0 + 3 * K32g);    // A rows 96-127
    gl2lds16(Bb,         bS + k0);               // B rows 0-31
    gl2lds16(Bb + 2048,  bS + k0 + K32g);        // B rows 32-63
    gl2lds16(Bb + 4096,  bS + k0 + 2 * K32g);    // B rows 64-95
    if constexpr (BN == 128)
      gl2lds16(Bb + 6144, bS + k0 + 3 * K32g);   // B rows 96-127
  };

  // read-side swizzled slots (per-lane constants)
  const int rx = lr & 7;
  const int arow = wr * 64 + lr;            // + i*16
  const int brow = wc * (BN / 2) + lr;      // + j*16

  const int nt = K >> 6;                    // BK=64 tiles (12 or 48)
  stage(0, 0);
  stage(1, 64);

  for (int t = 0; t < nt; ++t) {
    const int cur = t & 1;
    // counted wait: tile t's own loads done; tile t+1's stay in flight
    if (t == nt - 1) {
      asm volatile("s_waitcnt vmcnt(0)" ::: "memory");
    } else {
      if constexpr (BN == 128) asm volatile("s_waitcnt vmcnt(8)" ::: "memory");
      else                     asm volatile("s_waitcnt vmcnt(7)" ::: "memory");
    }
    asm volatile("s_barrier" ::: "memory");          // all waves: tile t ready

    const __hip_bfloat16* Ab = As + cur * ABUF;
    const __hip_bfloat16* Bb = Bs + cur * BBUF;
    bf16x8s af[2][4], bq[2][NF];
#pragma unroll
    for (int kk = 0; kk < 2; kk++) {
      const int sl = ((kk * 4 + kg) ^ rx) * 8;
#pragma unroll
      for (int i = 0; i < 4; i++)
        af[kk][i] = *reinterpret_cast<const bf16x8s*>(&Ab[(arow + i * 16) * 64 + sl]);
#pragma unroll
      for (int j = 0; j < NF; j++)
        bq[kk][j] = *reinterpret_cast<const bf16x8s*>(&Bb[(brow + j * 16) * 64 + sl]);
    }
    asm volatile("s_waitcnt lgkmcnt(0)" ::: "memory");  // frags in regs
    asm volatile("s_barrier" ::: "memory");             // all waves done reading

    if (t + 2 < nt) stage(cur, (t + 2) << 6);  // overwrite just-read buffer

#pragma unroll
    for (int kk = 0; kk < 2; kk++)
#pragma unroll
      for (int i = 0; i < 4; i++)
#pragma unroll
        for (int j = 0; j < NF; j++)
          acc[i][j] = __builtin_amdgcn_mfma_f32_16x16x32_bf16(
              af[kk][i], bq[kk][j], acc[i][j], 0, 0, 0);
  }

#pragma unroll
  for (int i = 0; i < 4; i++)
#pragma unroll
    for (int j = 0; j < NF; j++) {
      int col = n0 + wc * (BN / 2) + j * 16 + lr;
      float bv = bias[col];
#pragma unroll
      for (int r = 0; r < 4; r++) {
        int row = m0 + wr * 64 + i * 16 + kg * 4 + r;
        float v = acc[i][j][r] + bv;
        if (ACT == 1) v = 1.f / (1.f + __expf(-v));
        else if (ACT == 2) {
          float x = v;
          float z = 1.5957691216057308f * (x + 0.044715f * x * x * x);
          v = x / (1.f + __expf(-z));
        }
        if (RADD) v += __bfloat162float(R[(size_t)row * N + col]);
        Cb[(size_t)row * N + col] = __float2bfloat16(v);
      }
    }
}

// ---------------------------------------------------------------------------
extern "C" void kernel_launch(void* const* d_in, const int* in_sizes, int n_in,
                              void* d_out, int out_size, void* d_ws, size_t ws_size,
                              hipStream_t stream)
{
  const int*   ids  = (const int*)d_in[0];
  const float* wemb = (const float*)d_in[1];
  const float* pemb = (const float*)d_in[2];
  const float* elns = (const float*)d_in[3];
  const float* elnb = (const float*)d_in[4];
  const float* retW = (const float*)d_in[5];
  const float* retb = (const float*)d_in[6];
  const float* ln1s = (const float*)d_in[7];
  const float* ln1b = (const float*)d_in[8];
  const float* W1   = (const float*)d_in[9];
  const float* b1   = (const float*)d_in[10];
  const float* W2   = (const float*)d_in[11];
  const float* b2   = (const float*)d_in[12];
  const float* ln2s = (const float*)d_in[13];
  const float* ln2b = (const float*)d_in[14];
  const float* fins = (const float*)d_in[15];
  const float* finb = (const float*)d_in[16];
  float* out = (float*)d_out;

  char* ws = (char*)d_ws;
  size_t off = 0;
  __hip_bfloat16* retWt = (__hip_bfloat16*)(ws + off); off += (size_t)NL * HD * HD * 2;
  __hip_bfloat16* W1t   = (__hip_bfloat16*)(ws + off); off += (size_t)NL * HD * ID * 2;
  __hip_bfloat16* W2t   = (__hip_bfloat16*)(ws + off); off += (size_t)NL * ID * HD * 2;
  __hip_bfloat16* hb    = (__hip_bfloat16*)(ws + off); off += (size_t)ROWS * HD * 2;  // residual h
  __hip_bfloat16* h1b   = (__hip_bfloat16*)(ws + off); off += (size_t)ROWS * HD * 2;  // h1
  __hip_bfloat16* zb    = (__hip_bfloat16*)(ws + off); off += (size_t)ROWS * HD * 2;  // h+r / h1+ffn2
  __hip_bfloat16* gb    = (__hip_bfloat16*)(ws + off); off += (size_t)ROWS * ID * 2;  // s / gelu out
  __hip_bfloat16* sb = gb;
  __hip_bfloat16* yb = zb;

  dim3 tb(32, 8);
  transpose_bf16_kernel<<<dim3(HD/32, HD/32, NL), tb, 0, stream>>>(retW, retWt, HD, HD);
  transpose_bf16_kernel<<<dim3(ID/32, HD/32, NL), tb, 0, stream>>>(W1, W1t, HD, ID);
  transpose_bf16_kernel<<<dim3(HD/32, ID/32, NL), tb, 0, stream>>>(W2, W2t, ID, HD);

  embed_ln_kernel<<<ROWS/4, 256, 0, stream>>>(ids, wemb, pemb, elns, elnb, hb);

  for (int l = 0; l < NL; l++) {
    // s = sigmoid(h @ retW + rb) -> sb (bf16). BN=96 (512 blocks = 2/CU)
    gemm_mfma_kernel<96, 1, 0><<<dim3(ROWS/128, HD/96), 256, 0, stream>>>(
        hb, retWt + (size_t)l * HD * HD, retb + (size_t)l * HD,
        nullptr, sb, ROWS, HD, HD);
    // z = h + retention(s) -> zb (bf16)
    scan_kernel<<<NB * 32 * 3, 256, 0, stream>>>(sb, hb, zb);
    // h1 = LN(z)
    ln_row_kernel<0><<<ROWS/4, 256, 0, stream>>>(zb,
        ln1s + (size_t)l * HD, ln1b + (size_t)l * HD, h1b, nullptr);
    // g = gelu(h1 @ W1 + b1) -> gb (bf16). BN=128 (1536 blocks)
    gemm_mfma_kernel<128, 2, 0><<<dim3(ROWS/128, ID/128), 256, 0, stream>>>(
        h1b, W1t + (size_t)l * ID * HD, b1 + (size_t)l * ID,
        nullptr, gb, ROWS, ID, HD);
    // y = h1 + (g @ W2 + b2) -> yb (bf16). BN=96 (512 blocks = 2/CU)
    gemm_mfma_kernel<96, 0, 1><<<dim3(ROWS/128, HD/96), 256, 0, stream>>>(
        gb, W2t + (size_t)l * HD * ID, b2 + (size_t)l * HD,
        h1b, yb, ROWS, HD, ID);
    // h = LN(y)
    ln_row_kernel<0><<<ROWS/4, 256, 0, stream>>>(yb,
        ln2s + (size_t)l * HD, ln2b + (size_t)l * HD, hb, nullptr);
  }
  // final LN -> d_out (f32)
  ln_row_kernel<1><<<ROWS/4, 256, 0, stream>>>(hb, fins, finb, nullptr, out);
}